// Round 3
// baseline (523.529 us; speedup 1.0000x reference)
//
#include <hip/hip_runtime.h>

typedef unsigned short ushort_t;
typedef unsigned int uint_t;

typedef short bf16x8 __attribute__((ext_vector_type(8)));
typedef float f32x4 __attribute__((ext_vector_type(4)));

#define DIM 128

__device__ __forceinline__ float bf2f(ushort_t u) {
    uint_t x = ((uint_t)u) << 16;
    float f;
    __builtin_memcpy(&f, &x, 4);
    return f;
}

__device__ __forceinline__ ushort_t f2bf(float f) {
    uint_t x;
    __builtin_memcpy(&x, &f, 4);
    uint_t r = (x + 0x7fffu + ((x >> 16) & 1u)) >> 16;
    return (ushort_t)r;
}

// ---------- conversion kernels ----------

__global__ void k_cvt_f32_bf16(const float* __restrict__ in, ushort_t* __restrict__ out, int n4) {
    int i = blockIdx.x * blockDim.x + threadIdx.x;
    if (i < n4) {
        float4 f = ((const float4*)in)[i];
        ushort4 u;
        u.x = f2bf(f.x); u.y = f2bf(f.y); u.z = f2bf(f.z); u.w = f2bf(f.w);
        ((ushort4*)out)[i] = u;
    }
}

// all four weight transposes in one launch: WT[n*128+k] = bf16(W[k*128+n])
__global__ void k_wt4(const float* __restrict__ W0, const float* __restrict__ W1,
                      const float* __restrict__ W2, const float* __restrict__ W3,
                      ushort_t* __restrict__ T0, ushort_t* __restrict__ T1,
                      ushort_t* __restrict__ T2, ushort_t* __restrict__ T3) {
    int i = blockIdx.x * blockDim.x + threadIdx.x;  // 4*16384
    int w = i >> 14, j = i & 16383;
    int n = j >> 7, k = j & 127;
    const float* W = (w == 0) ? W0 : (w == 1) ? W1 : (w == 2) ? W2 : W3;
    ushort_t* T = (w == 0) ? T0 : (w == 1) ? T1 : (w == 2) ? T2 : T3;
    T[j] = f2bf(W[k * DIM + n]);
}

// ---------- CSR build ----------
// Both edge passes are latency-bound on L2 atomics; unroll x8 so each thread
// keeps 8 independent atomic chains in flight.

__global__ void k_deg(const int* __restrict__ dst, int E, int* __restrict__ deg) {
    int i0 = (blockIdx.x * blockDim.x + threadIdx.x) * 8;
    if (i0 + 8 <= E) {
        int4 d0 = *(const int4*)(dst + i0);
        int4 d1 = *(const int4*)(dst + i0 + 4);
        atomicAdd(&deg[d0.x], 1); atomicAdd(&deg[d0.y], 1);
        atomicAdd(&deg[d0.z], 1); atomicAdd(&deg[d0.w], 1);
        atomicAdd(&deg[d1.x], 1); atomicAdd(&deg[d1.y], 1);
        atomicAdd(&deg[d1.z], 1); atomicAdd(&deg[d1.w], 1);
    } else {
        for (int i = i0; i < E; i++) atomicAdd(&deg[dst[i]], 1);
    }
}

__global__ void k_scan_chunks(const int* __restrict__ deg, int n,
                              int* __restrict__ excl, int* __restrict__ bsum) {
    __shared__ int lds[1024];
    int t = threadIdx.x;
    int i = blockIdx.x * 1024 + t;
    int v = (i < n) ? deg[i] : 0;
    lds[t] = v;
    __syncthreads();
    for (int off = 1; off < 1024; off <<= 1) {
        int u = (t >= off) ? lds[t - off] : 0;
        __syncthreads();
        lds[t] += u;
        __syncthreads();
    }
    if (i < n) excl[i] = lds[t] - v;
    if (t == 1023) bsum[blockIdx.x] = lds[1023];
}

__global__ void k_scan_tops(const int* __restrict__ bsum, int nc, int* __restrict__ boff) {
    __shared__ int lds[128];
    int t = threadIdx.x;
    int v = (t < nc) ? bsum[t] : 0;
    lds[t] = v;
    __syncthreads();
    for (int off = 1; off < 128; off <<= 1) {
        int u = (t >= off) ? lds[t - off] : 0;
        __syncthreads();
        lds[t] += u;
        __syncthreads();
    }
    boff[t] = lds[t] - v;
}

__global__ void k_finalize(const int* __restrict__ excl, const int* __restrict__ boff,
                           int n, int E, int* __restrict__ row_ptr, int* __restrict__ cursor) {
    int i = blockIdx.x * blockDim.x + threadIdx.x;
    if (i < n) {
        int v = excl[i] + boff[i >> 10];
        row_ptr[i] = v;
        cursor[i] = v;
        if (i == 0) row_ptr[n] = E;
    }
}

__global__ void k_fill(const int* __restrict__ src, const int* __restrict__ dst, int E,
                       int* __restrict__ cursor, int* __restrict__ csr_src) {
    int i0 = (blockIdx.x * blockDim.x + threadIdx.x) * 8;
    if (i0 + 8 <= E) {
        int4 d0 = *(const int4*)(dst + i0);
        int4 d1 = *(const int4*)(dst + i0 + 4);
        int4 s0 = *(const int4*)(src + i0);
        int4 s1 = *(const int4*)(src + i0 + 4);
        int p0 = atomicAdd(&cursor[d0.x], 1);
        int p1 = atomicAdd(&cursor[d0.y], 1);
        int p2 = atomicAdd(&cursor[d0.z], 1);
        int p3 = atomicAdd(&cursor[d0.w], 1);
        int p4 = atomicAdd(&cursor[d1.x], 1);
        int p5 = atomicAdd(&cursor[d1.y], 1);
        int p6 = atomicAdd(&cursor[d1.z], 1);
        int p7 = atomicAdd(&cursor[d1.w], 1);
        csr_src[p0] = s0.x; csr_src[p1] = s0.y; csr_src[p2] = s0.z; csr_src[p3] = s0.w;
        csr_src[p4] = s1.x; csr_src[p5] = s1.y; csr_src[p6] = s1.z; csr_src[p7] = s1.w;
    } else {
        for (int i = i0; i < E; i++) {
            int p = atomicAdd(&cursor[dst[i]], 1);
            csr_src[p] = src[i];
        }
    }
}

// ---------- mean aggregation: 16 lanes per node, x4 edge unroll ----------

__device__ __forceinline__ void acc8(float* a, uint4 p) {
    a[0] += bf2f((ushort_t)(p.x & 0xffffu));
    a[1] += bf2f((ushort_t)(p.x >> 16));
    a[2] += bf2f((ushort_t)(p.y & 0xffffu));
    a[3] += bf2f((ushort_t)(p.y >> 16));
    a[4] += bf2f((ushort_t)(p.z & 0xffffu));
    a[5] += bf2f((ushort_t)(p.z >> 16));
    a[6] += bf2f((ushort_t)(p.w & 0xffffu));
    a[7] += bf2f((ushort_t)(p.w >> 16));
}

__global__ __launch_bounds__(256) void k_agg(const ushort_t* __restrict__ X,
                                             const int* __restrict__ row_ptr,
                                             const int* __restrict__ csr,
                                             ushort_t* __restrict__ out, int n) {
    int node = (int)((blockIdx.x * (unsigned)blockDim.x + threadIdx.x) >> 4);
    if (node >= n) return;
    int sl = threadIdx.x & 15;               // sub-lane: 8 bf16 = 16 B of the row
    int beg = row_ptr[node], end = row_ptr[node + 1];
    float a[8] = {0.f, 0.f, 0.f, 0.f, 0.f, 0.f, 0.f, 0.f};

    int e = beg;
    for (; e + 4 <= end; e += 4) {
        int s0 = csr[e + 0], s1 = csr[e + 1], s2 = csr[e + 2], s3 = csr[e + 3];
        uint4 p0 = *(const uint4*)(X + (size_t)s0 * DIM + sl * 8);
        uint4 p1 = *(const uint4*)(X + (size_t)s1 * DIM + sl * 8);
        uint4 p2 = *(const uint4*)(X + (size_t)s2 * DIM + sl * 8);
        uint4 p3 = *(const uint4*)(X + (size_t)s3 * DIM + sl * 8);
        acc8(a, p0); acc8(a, p1); acc8(a, p2); acc8(a, p3);
    }
    for (; e < end; e++) {
        int s = csr[e];
        uint4 p = *(const uint4*)(X + (size_t)s * DIM + sl * 8);
        acc8(a, p);
    }

    int cnt = end - beg;
    float sc = (cnt > 0) ? 1.f / (float)cnt : 0.f;
    uint4 o;
    o.x = (uint_t)f2bf(a[0] * sc) | ((uint_t)f2bf(a[1] * sc) << 16);
    o.y = (uint_t)f2bf(a[2] * sc) | ((uint_t)f2bf(a[3] * sc) << 16);
    o.z = (uint_t)f2bf(a[4] * sc) | ((uint_t)f2bf(a[5] * sc) << 16);
    o.w = (uint_t)f2bf(a[6] * sc) | ((uint_t)f2bf(a[7] * sc) << 16);
    *(uint4*)(out + (size_t)node * DIM + sl * 8) = o;
}

// ---------- fused GEMM: out = A1*W_l + A2*W_r + b, 32 rows per wave ----------
// MFMA 16x16x32 bf16 layouts (m89-verified):
//   A frag: lane holds A[m=lane&15][k=quad*8+j]
//   B frag: lane holds B[k=quad*8+j][n=lane&15] = WT[n=lane&15][k=quad*8+j]
//   C/D   : col=lane&15, row=quad*4+reg

template <bool RELU, bool OUT_BF16>
__global__ __launch_bounds__(256) void k_gemm(const ushort_t* __restrict__ A1,
                                              const ushort_t* __restrict__ A2,
                                              const ushort_t* __restrict__ WTl,
                                              const ushort_t* __restrict__ WTr,
                                              const float* __restrict__ bias,
                                              void* __restrict__ Out, int n_waves, int M) {
    int wave = (int)((blockIdx.x * (unsigned)blockDim.x + threadIdx.x) >> 6);
    if (wave >= n_waves) return;
    int lane = threadIdx.x & 63;
    int col = lane & 15;
    int quad = lane >> 4;

    // two 16-row M-tiles per wave
    bf16x8 a[2][8];
#pragma unroll
    for (int t = 0; t < 2; t++) {
        int arow = wave * 32 + t * 16 + col;
        const ushort_t* a1p = A1 + (size_t)arow * DIM + quad * 8;
        const ushort_t* a2p = A2 + (size_t)arow * DIM + quad * 8;
#pragma unroll
        for (int ks = 0; ks < 4; ks++) a[t][ks] = *(const bf16x8*)(a1p + ks * 32);
#pragma unroll
        for (int ks = 0; ks < 4; ks++) a[t][4 + ks] = *(const bf16x8*)(a2p + ks * 32);
    }

    f32x4 acc[2][8];
#pragma unroll
    for (int t = 0; t < 2; t++)
#pragma unroll
        for (int nt = 0; nt < 8; nt++) acc[t][nt] = (f32x4){0.f, 0.f, 0.f, 0.f};

#pragma unroll
    for (int nt = 0; nt < 8; nt++) {
        const ushort_t* bl = WTl + (size_t)(nt * 16 + col) * DIM + quad * 8;
        const ushort_t* br = WTr + (size_t)(nt * 16 + col) * DIM + quad * 8;
#pragma unroll
        for (int ks = 0; ks < 4; ks++) {
            bf16x8 b = *(const bf16x8*)(bl + ks * 32);
            acc[0][nt] = __builtin_amdgcn_mfma_f32_16x16x32_bf16(a[0][ks], b, acc[0][nt], 0, 0, 0);
            acc[1][nt] = __builtin_amdgcn_mfma_f32_16x16x32_bf16(a[1][ks], b, acc[1][nt], 0, 0, 0);
        }
#pragma unroll
        for (int ks = 0; ks < 4; ks++) {
            bf16x8 b = *(const bf16x8*)(br + ks * 32);
            acc[0][nt] = __builtin_amdgcn_mfma_f32_16x16x32_bf16(a[0][4 + ks], b, acc[0][nt], 0, 0, 0);
            acc[1][nt] = __builtin_amdgcn_mfma_f32_16x16x32_bf16(a[1][4 + ks], b, acc[1][nt], 0, 0, 0);
        }
    }

#pragma unroll
    for (int t = 0; t < 2; t++)
#pragma unroll
        for (int nt = 0; nt < 8; nt++) {
            int c = nt * 16 + col;
            float bv = bias[c];
#pragma unroll
            for (int r = 0; r < 4; r++) {
                int m = wave * 32 + t * 16 + quad * 4 + r;
                if (m < M) {
                    float v = acc[t][nt][r] + bv;
                    if (RELU) v = v > 0.f ? v : 0.f;
                    if (OUT_BF16)
                        ((ushort_t*)Out)[(size_t)m * DIM + c] = f2bf(v);
                    else
                        ((float*)Out)[(size_t)m * DIM + c] = v;
                }
            }
        }
}

// ---------- host ----------

extern "C" void kernel_launch(void* const* d_in, const int* in_sizes, int n_in,
                              void* d_out, int out_size, void* d_ws, size_t ws_size,
                              hipStream_t stream) {
    const int N = in_sizes[0] / DIM;   // 100000
    const int E = in_sizes[1] / 2;     // 1600000

    const float* x   = (const float*)d_in[0];
    const int*   ei  = (const int*)d_in[1];
    const int*   src = ei;
    const int*   dst = ei + E;
    const float* W1l = (const float*)d_in[2];
    const float* b1  = (const float*)d_in[3];
    const float* W1r = (const float*)d_in[4];
    const float* W2l = (const float*)d_in[5];
    const float* b2  = (const float*)d_in[6];
    const float* W2r = (const float*)d_in[7];
    float* out = (float*)d_out;

    char* ws = (char*)d_ws;
    size_t off = 0;
    auto alloc = [&](size_t bytes) -> char* {
        char* p = ws + off;
        off = (off + bytes + 255) & ~(size_t)255;
        return p;
    };

    const int nc = (N + 1023) / 1024;                 // scan chunks (98)
    int*      deg     = (int*)alloc((size_t)N * 4);
    int*      excl    = (int*)alloc((size_t)N * 4);
    int*      bsum    = (int*)alloc(128 * 4);
    int*      boff    = (int*)alloc(132 * 4);
    int*      row_ptr = (int*)alloc((size_t)(N + 1) * 4);
    int*      cursor  = (int*)alloc((size_t)N * 4);
    int*      csr     = (int*)alloc((size_t)E * 4);
    size_t    fpad    = (size_t)32 * DIM * 2;         // tile-padding for MFMA A loads
    ushort_t* xb      = (ushort_t*)alloc((size_t)N * DIM * 2 + fpad);
    ushort_t* hb      = (ushort_t*)alloc((size_t)N * DIM * 2 + fpad);
    ushort_t* aggb    = (ushort_t*)alloc((size_t)N * DIM * 2 + fpad);
    ushort_t* wt1l    = (ushort_t*)alloc((size_t)DIM * DIM * 2);
    ushort_t* wt1r    = (ushort_t*)alloc((size_t)DIM * DIM * 2);
    ushort_t* wt2l    = (ushort_t*)alloc((size_t)DIM * DIM * 2);
    ushort_t* wt2r    = (ushort_t*)alloc((size_t)DIM * DIM * 2);

    // zero degree histogram (ws is poisoned each call)
    hipMemsetAsync(deg, 0, (size_t)N * 4, stream);

    // x -> bf16
    {
        int n4 = N * DIM / 4;
        k_cvt_f32_bf16<<<dim3((n4 + 255) / 256), dim3(256), 0, stream>>>(x, xb, n4);
    }
    // weights -> transposed bf16 (single launch)
    k_wt4<<<dim3(4 * DIM * DIM / 256), dim3(256), 0, stream>>>(W1l, W1r, W2l, W2r,
                                                               wt1l, wt1r, wt2l, wt2r);
    // CSR build (x8 unrolled edge passes)
    {
        int t8 = (E + 7) / 8;
        k_deg<<<dim3((t8 + 255) / 256), dim3(256), 0, stream>>>(dst, E, deg);
        k_scan_chunks<<<dim3(nc), dim3(1024), 0, stream>>>(deg, N, excl, bsum);
        k_scan_tops<<<dim3(1), dim3(128), 0, stream>>>(bsum, nc, boff);
        k_finalize<<<dim3((N + 255) / 256), dim3(256), 0, stream>>>(excl, boff, N, E, row_ptr, cursor);
        k_fill<<<dim3((t8 + 255) / 256), dim3(256), 0, stream>>>(src, dst, E, cursor, csr);
    }

    const int n_waves = (N + 31) / 32;                          // 3125 (32 rows/wave)
    dim3 gemm_grid((n_waves + 3) / 4), gemm_blk(256);
    dim3 agg_grid((N + 15) / 16), agg_blk(256);                 // 16 nodes/block (16 lanes/node)

    // layer 1
    k_agg<<<agg_grid, agg_blk, 0, stream>>>(xb, row_ptr, csr, aggb, N);
    k_gemm<true, true><<<gemm_grid, gemm_blk, 0, stream>>>(aggb, xb, wt1l, wt1r, b1, hb, n_waves, N);
    // layer 2
    k_agg<<<agg_grid, agg_blk, 0, stream>>>(hb, row_ptr, csr, aggb, N);
    k_gemm<false, false><<<gemm_grid, gemm_blk, 0, stream>>>(aggb, hb, wt2l, wt2r, b2, out, n_waves, N);

    (void)n_in; (void)out_size; (void)ws_size;
}

// Round 4
// 391.545 us; speedup vs baseline: 1.3371x; 1.3371x over previous
//
#include <hip/hip_runtime.h>

typedef unsigned short ushort_t;
typedef unsigned int uint_t;

typedef short bf16x8 __attribute__((ext_vector_type(8)));
typedef float f32x4 __attribute__((ext_vector_type(4)));

#define DIM 128
#define BSHIFT 8
#define BNODES 256           // nodes per bucket (1<<BSHIFT)

__device__ __forceinline__ float bf2f(ushort_t u) {
    uint_t x = ((uint_t)u) << 16;
    float f;
    __builtin_memcpy(&f, &x, 4);
    return f;
}

__device__ __forceinline__ ushort_t f2bf(float f) {
    uint_t x;
    __builtin_memcpy(&x, &f, 4);
    uint_t r = (x + 0x7fffu + ((x >> 16) & 1u)) >> 16;
    return (ushort_t)r;
}

// ---------- conversion kernels ----------

__global__ void k_cvt_f32_bf16(const float* __restrict__ in, ushort_t* __restrict__ out, int n4) {
    int i = blockIdx.x * blockDim.x + threadIdx.x;
    if (i < n4) {
        float4 f = ((const float4*)in)[i];
        ushort4 u;
        u.x = f2bf(f.x); u.y = f2bf(f.y); u.z = f2bf(f.z); u.w = f2bf(f.w);
        ((ushort4*)out)[i] = u;
    }
}

// all four weight transposes in one launch: WT[n*128+k] = bf16(W[k*128+n])
__global__ void k_wt4(const float* __restrict__ W0, const float* __restrict__ W1,
                      const float* __restrict__ W2, const float* __restrict__ W3,
                      ushort_t* __restrict__ T0, ushort_t* __restrict__ T1,
                      ushort_t* __restrict__ T2, ushort_t* __restrict__ T3) {
    int i = blockIdx.x * blockDim.x + threadIdx.x;  // 4*16384
    int w = i >> 14, j = i & 16383;
    int n = j >> 7, k = j & 127;
    const float* W = (w == 0) ? W0 : (w == 1) ? W1 : (w == 2) ? W2 : W3;
    ushort_t* T = (w == 0) ? T0 : (w == 1) ? T1 : (w == 2) ? T2 : T3;
    T[j] = f2bf(W[k * DIM + n]);
}

// ---------- CSR build via two-level bucket counting sort ----------
// Device-scope atomics execute at the coherence point (memory-side) on 8-XCD
// parts and cap at ~13 G ops/s; so we do histogram/rank work in LDS and touch
// global atomics only ~0.2M times (per-(block,bucket) reservations).

// P0: global bucket histogram (LDS-privatized)
__global__ __launch_bounds__(256) void k_bhist(const int* __restrict__ dst, int E, int NB,
                                               int* __restrict__ bucketCount) {
    __shared__ int hist[512];
    int t = threadIdx.x;
    for (int b = t; b < NB; b += 256) hist[b] = 0;
    __syncthreads();
    int per = (E + gridDim.x - 1) / gridDim.x;
    int beg = blockIdx.x * per, end = min(beg + per, E);
    for (int i = beg + t; i < end; i += 256)
        atomicAdd(&hist[dst[i] >> BSHIFT], 1);
    __syncthreads();
    for (int b = t; b < NB; b += 256) {
        int v = hist[b];
        if (v) atomicAdd(&bucketCount[b], v);
    }
}

// S0: exclusive scan of bucket counts (NB <= 512); init cursor; row_ptr[N]=E
__global__ __launch_bounds__(512) void k_bscan(const int* __restrict__ bucketCount, int NB, int E,
                                               int* __restrict__ bucketBase,
                                               int* __restrict__ bucketCursor,
                                               int* __restrict__ row_ptr, int N) {
    __shared__ int lds[512];
    int t = threadIdx.x;
    int v = (t < NB) ? bucketCount[t] : 0;
    lds[t] = v;
    __syncthreads();
    for (int off = 1; off < 512; off <<= 1) {
        int u = (t >= off) ? lds[t - off] : 0;
        __syncthreads();
        lds[t] += u;
        __syncthreads();
    }
    if (t < NB) {
        int b = lds[t] - v;
        bucketBase[t] = b;
        bucketCursor[t] = b;
    }
    if (t == 0) row_ptr[N] = E;
}

// P1: scatter edges into bucket segments, packed (dstLocal<<24 | src)
__global__ __launch_bounds__(256) void k_bucketize(const int* __restrict__ src,
                                                   const int* __restrict__ dst, int E, int NB,
                                                   int* __restrict__ bucketCursor,
                                                   uint_t* __restrict__ bebuf) {
    __shared__ int hist[512];
    __shared__ int base[512];
    int t = threadIdx.x;
    for (int b = t; b < NB; b += 256) hist[b] = 0;
    __syncthreads();
    int per = (E + gridDim.x - 1) / gridDim.x;
    int beg = blockIdx.x * per, end = min(beg + per, E);
    for (int i = beg + t; i < end; i += 256)
        atomicAdd(&hist[dst[i] >> BSHIFT], 1);
    __syncthreads();
    for (int b = t; b < NB; b += 256) {
        int v = hist[b];
        base[b] = v ? atomicAdd(&bucketCursor[b], v) : 0;
        hist[b] = 0;
    }
    __syncthreads();
    for (int i = beg + t; i < end; i += 256) {
        int d = dst[i], s = src[i];
        int b = d >> BSHIFT;
        int off = atomicAdd(&hist[b], 1);
        bebuf[base[b] + off] = ((uint_t)(d & (BNODES - 1)) << 24) | (uint_t)s;
    }
}

// P2: per-bucket local counting sort -> row_ptr + csr (all LDS atomics)
__global__ __launch_bounds__(256) void k_bcsr(const uint_t* __restrict__ bebuf,
                                              const int* __restrict__ bucketBase,
                                              const int* __restrict__ bucketCount, int N,
                                              int* __restrict__ row_ptr, int* __restrict__ csr) {
    __shared__ int hist[BNODES];
    __shared__ int cur[BNODES];
    int t = threadIdx.x;
    int b = blockIdx.x;
    int ebase = bucketBase[b], cnt = bucketCount[b];
    int nodeBase = b << BSHIFT;
    hist[t] = 0;
    __syncthreads();
    for (int i = t; i < cnt; i += 256)
        atomicAdd(&hist[bebuf[ebase + i] >> 24], 1);
    __syncthreads();
    int v = hist[t];
    for (int off = 1; off < 256; off <<= 1) {
        int u = (t >= off) ? hist[t - off] : 0;
        __syncthreads();
        hist[t] += u;
        __syncthreads();
    }
    int excl = hist[t] - v;
    int node = nodeBase + t;
    if (node < N) row_ptr[node] = ebase + excl;
    cur[t] = excl;
    __syncthreads();
    for (int i = t; i < cnt; i += 256) {
        uint_t e = bebuf[ebase + i];
        int dl = (int)(e >> 24);
        int pos = atomicAdd(&cur[dl], 1);
        csr[ebase + pos] = (int)(e & 0xFFFFFFu);
    }
}

// ---------- mean aggregation: 16 lanes per node, x4 edge unroll ----------

__device__ __forceinline__ void acc8(float* a, uint4 p) {
    a[0] += bf2f((ushort_t)(p.x & 0xffffu));
    a[1] += bf2f((ushort_t)(p.x >> 16));
    a[2] += bf2f((ushort_t)(p.y & 0xffffu));
    a[3] += bf2f((ushort_t)(p.y >> 16));
    a[4] += bf2f((ushort_t)(p.z & 0xffffu));
    a[5] += bf2f((ushort_t)(p.z >> 16));
    a[6] += bf2f((ushort_t)(p.w & 0xffffu));
    a[7] += bf2f((ushort_t)(p.w >> 16));
}

__global__ __launch_bounds__(256) void k_agg(const ushort_t* __restrict__ X,
                                             const int* __restrict__ row_ptr,
                                             const int* __restrict__ csr,
                                             ushort_t* __restrict__ out, int n) {
    int node = (int)((blockIdx.x * (unsigned)blockDim.x + threadIdx.x) >> 4);
    if (node >= n) return;
    int sl = threadIdx.x & 15;               // sub-lane: 8 bf16 = 16 B of the row
    int beg = row_ptr[node], end = row_ptr[node + 1];
    float a[8] = {0.f, 0.f, 0.f, 0.f, 0.f, 0.f, 0.f, 0.f};

    int e = beg;
    for (; e + 4 <= end; e += 4) {
        int s0 = csr[e + 0], s1 = csr[e + 1], s2 = csr[e + 2], s3 = csr[e + 3];
        uint4 p0 = *(const uint4*)(X + (size_t)s0 * DIM + sl * 8);
        uint4 p1 = *(const uint4*)(X + (size_t)s1 * DIM + sl * 8);
        uint4 p2 = *(const uint4*)(X + (size_t)s2 * DIM + sl * 8);
        uint4 p3 = *(const uint4*)(X + (size_t)s3 * DIM + sl * 8);
        acc8(a, p0); acc8(a, p1); acc8(a, p2); acc8(a, p3);
    }
    for (; e < end; e++) {
        int s = csr[e];
        uint4 p = *(const uint4*)(X + (size_t)s * DIM + sl * 8);
        acc8(a, p);
    }

    int cnt = end - beg;
    float sc = (cnt > 0) ? 1.f / (float)cnt : 0.f;
    uint4 o;
    o.x = (uint_t)f2bf(a[0] * sc) | ((uint_t)f2bf(a[1] * sc) << 16);
    o.y = (uint_t)f2bf(a[2] * sc) | ((uint_t)f2bf(a[3] * sc) << 16);
    o.z = (uint_t)f2bf(a[4] * sc) | ((uint_t)f2bf(a[5] * sc) << 16);
    o.w = (uint_t)f2bf(a[6] * sc) | ((uint_t)f2bf(a[7] * sc) << 16);
    *(uint4*)(out + (size_t)node * DIM + sl * 8) = o;
}

// ---------- fused GEMM: out = A1*W_l + A2*W_r + b, 32 rows per wave ----------
// MFMA 16x16x32 bf16 layouts (m89-verified):
//   A frag: lane holds A[m=lane&15][k=quad*8+j]
//   B frag: lane holds B[k=quad*8+j][n=lane&15] = WT[n=lane&15][k=quad*8+j]
//   C/D   : col=lane&15, row=quad*4+reg

template <bool RELU, bool OUT_BF16>
__global__ __launch_bounds__(256) void k_gemm(const ushort_t* __restrict__ A1,
                                              const ushort_t* __restrict__ A2,
                                              const ushort_t* __restrict__ WTl,
                                              const ushort_t* __restrict__ WTr,
                                              const float* __restrict__ bias,
                                              void* __restrict__ Out, int n_waves, int M) {
    int wave = (int)((blockIdx.x * (unsigned)blockDim.x + threadIdx.x) >> 6);
    if (wave >= n_waves) return;
    int lane = threadIdx.x & 63;
    int col = lane & 15;
    int quad = lane >> 4;

    // two 16-row M-tiles per wave
    bf16x8 a[2][8];
#pragma unroll
    for (int t = 0; t < 2; t++) {
        int arow = wave * 32 + t * 16 + col;
        const ushort_t* a1p = A1 + (size_t)arow * DIM + quad * 8;
        const ushort_t* a2p = A2 + (size_t)arow * DIM + quad * 8;
#pragma unroll
        for (int ks = 0; ks < 4; ks++) a[t][ks] = *(const bf16x8*)(a1p + ks * 32);
#pragma unroll
        for (int ks = 0; ks < 4; ks++) a[t][4 + ks] = *(const bf16x8*)(a2p + ks * 32);
    }

    f32x4 acc[2][8];
#pragma unroll
    for (int t = 0; t < 2; t++)
#pragma unroll
        for (int nt = 0; nt < 8; nt++) acc[t][nt] = (f32x4){0.f, 0.f, 0.f, 0.f};

#pragma unroll
    for (int nt = 0; nt < 8; nt++) {
        const ushort_t* bl = WTl + (size_t)(nt * 16 + col) * DIM + quad * 8;
        const ushort_t* br = WTr + (size_t)(nt * 16 + col) * DIM + quad * 8;
#pragma unroll
        for (int ks = 0; ks < 4; ks++) {
            bf16x8 b = *(const bf16x8*)(bl + ks * 32);
            acc[0][nt] = __builtin_amdgcn_mfma_f32_16x16x32_bf16(a[0][ks], b, acc[0][nt], 0, 0, 0);
            acc[1][nt] = __builtin_amdgcn_mfma_f32_16x16x32_bf16(a[1][ks], b, acc[1][nt], 0, 0, 0);
        }
#pragma unroll
        for (int ks = 0; ks < 4; ks++) {
            bf16x8 b = *(const bf16x8*)(br + ks * 32);
            acc[0][nt] = __builtin_amdgcn_mfma_f32_16x16x32_bf16(a[0][4 + ks], b, acc[0][nt], 0, 0, 0);
            acc[1][nt] = __builtin_amdgcn_mfma_f32_16x16x32_bf16(a[1][4 + ks], b, acc[1][nt], 0, 0, 0);
        }
    }

#pragma unroll
    for (int t = 0; t < 2; t++)
#pragma unroll
        for (int nt = 0; nt < 8; nt++) {
            int c = nt * 16 + col;
            float bv = bias[c];
#pragma unroll
            for (int r = 0; r < 4; r++) {
                int m = wave * 32 + t * 16 + quad * 4 + r;
                if (m < M) {
                    float v = acc[t][nt][r] + bv;
                    if (RELU) v = v > 0.f ? v : 0.f;
                    if (OUT_BF16)
                        ((ushort_t*)Out)[(size_t)m * DIM + c] = f2bf(v);
                    else
                        ((float*)Out)[(size_t)m * DIM + c] = v;
                }
            }
        }
}

// ---------- host ----------

extern "C" void kernel_launch(void* const* d_in, const int* in_sizes, int n_in,
                              void* d_out, int out_size, void* d_ws, size_t ws_size,
                              hipStream_t stream) {
    const int N = in_sizes[0] / DIM;   // 100000
    const int E = in_sizes[1] / 2;     // 1600000
    const int NB = (N + BNODES - 1) >> BSHIFT;   // 391 buckets

    const float* x   = (const float*)d_in[0];
    const int*   ei  = (const int*)d_in[1];
    const int*   src = ei;
    const int*   dst = ei + E;
    const float* W1l = (const float*)d_in[2];
    const float* b1  = (const float*)d_in[3];
    const float* W1r = (const float*)d_in[4];
    const float* W2l = (const float*)d_in[5];
    const float* b2  = (const float*)d_in[6];
    const float* W2r = (const float*)d_in[7];
    float* out = (float*)d_out;

    char* ws = (char*)d_ws;
    size_t off = 0;
    auto alloc = [&](size_t bytes) -> char* {
        char* p = ws + off;
        off = (off + bytes + 255) & ~(size_t)255;
        return p;
    };

    int*      bucketCount  = (int*)alloc((size_t)NB * 4);
    int*      bucketBase   = (int*)alloc((size_t)NB * 4);
    int*      bucketCursor = (int*)alloc((size_t)NB * 4);
    int*      row_ptr      = (int*)alloc((size_t)(N + 1) * 4);
    int*      csr          = (int*)alloc((size_t)E * 4);
    uint_t*   bebuf        = (uint_t*)alloc((size_t)E * 4);
    size_t    fpad         = (size_t)32 * DIM * 2;   // tile-padding for MFMA A loads
    ushort_t* xb           = (ushort_t*)alloc((size_t)N * DIM * 2 + fpad);
    ushort_t* hb           = (ushort_t*)alloc((size_t)N * DIM * 2 + fpad);
    ushort_t* aggb         = (ushort_t*)alloc((size_t)N * DIM * 2 + fpad);
    ushort_t* wt1l         = (ushort_t*)alloc((size_t)DIM * DIM * 2);
    ushort_t* wt1r         = (ushort_t*)alloc((size_t)DIM * DIM * 2);
    ushort_t* wt2l         = (ushort_t*)alloc((size_t)DIM * DIM * 2);
    ushort_t* wt2r         = (ushort_t*)alloc((size_t)DIM * DIM * 2);

    // zero bucket histogram (ws is poisoned each call)
    hipMemsetAsync(bucketCount, 0, (size_t)NB * 4, stream);

    // x -> bf16
    {
        int n4 = N * DIM / 4;
        k_cvt_f32_bf16<<<dim3((n4 + 255) / 256), dim3(256), 0, stream>>>(x, xb, n4);
    }
    // weights -> transposed bf16 (single launch)
    k_wt4<<<dim3(4 * DIM * DIM / 256), dim3(256), 0, stream>>>(W1l, W1r, W2l, W2r,
                                                               wt1l, wt1r, wt2l, wt2r);
    // CSR build: bucket counting sort
    k_bhist<<<dim3(256), dim3(256), 0, stream>>>(dst, E, NB, bucketCount);
    k_bscan<<<dim3(1), dim3(512), 0, stream>>>(bucketCount, NB, E, bucketBase, bucketCursor, row_ptr, N);
    k_bucketize<<<dim3(256), dim3(256), 0, stream>>>(src, dst, E, NB, bucketCursor, bebuf);
    k_bcsr<<<dim3(NB), dim3(256), 0, stream>>>(bebuf, bucketBase, bucketCount, N, row_ptr, csr);

    const int n_waves = (N + 31) / 32;                          // 3125 (32 rows/wave)
    dim3 gemm_grid((n_waves + 3) / 4), gemm_blk(256);
    dim3 agg_grid((N + 15) / 16), agg_blk(256);                 // 16 nodes/block (16 lanes/node)

    // layer 1
    k_agg<<<agg_grid, agg_blk, 0, stream>>>(xb, row_ptr, csr, aggb, N);
    k_gemm<true, true><<<gemm_grid, gemm_blk, 0, stream>>>(aggb, xb, wt1l, wt1r, b1, hb, n_waves, N);
    // layer 2
    k_agg<<<agg_grid, agg_blk, 0, stream>>>(hb, row_ptr, csr, aggb, N);
    k_gemm<false, false><<<gemm_grid, gemm_blk, 0, stream>>>(aggb, hb, wt2l, wt2r, b2, out, n_waves, N);

    (void)n_in; (void)out_size; (void)ws_size;
}

// Round 5
// 357.757 us; speedup vs baseline: 1.4634x; 1.0944x over previous
//
#include <hip/hip_runtime.h>

typedef unsigned short ushort_t;
typedef unsigned int uint_t;

typedef short bf16x8 __attribute__((ext_vector_type(8)));
typedef float f32x4 __attribute__((ext_vector_type(4)));

#define DIM 128
#define BSHIFT 8
#define BNODES 256           // nodes per bucket (1<<BSHIFT)

__device__ __forceinline__ float bf2f(ushort_t u) {
    uint_t x = ((uint_t)u) << 16;
    float f;
    __builtin_memcpy(&f, &x, 4);
    return f;
}

__device__ __forceinline__ ushort_t f2bf(float f) {
    uint_t x;
    __builtin_memcpy(&x, &f, 4);
    uint_t r = (x + 0x7fffu + ((x >> 16) & 1u)) >> 16;
    return (ushort_t)r;
}

// ---------- conversion kernels ----------

__global__ void k_cvt_f32_bf16(const float* __restrict__ in, ushort_t* __restrict__ out, int n4) {
    int i = blockIdx.x * blockDim.x + threadIdx.x;
    if (i < n4) {
        float4 f = ((const float4*)in)[i];
        ushort4 u;
        u.x = f2bf(f.x); u.y = f2bf(f.y); u.z = f2bf(f.z); u.w = f2bf(f.w);
        ((ushort4*)out)[i] = u;
    }
}

// all four weight transposes in one launch: WT[n*128+k] = bf16(W[k*128+n])
__global__ void k_wt4(const float* __restrict__ W0, const float* __restrict__ W1,
                      const float* __restrict__ W2, const float* __restrict__ W3,
                      ushort_t* __restrict__ T0, ushort_t* __restrict__ T1,
                      ushort_t* __restrict__ T2, ushort_t* __restrict__ T3) {
    int i = blockIdx.x * blockDim.x + threadIdx.x;  // 4*16384
    int w = i >> 14, j = i & 16383;
    int n = j >> 7, k = j & 127;
    const float* W = (w == 0) ? W0 : (w == 1) ? W1 : (w == 2) ? W2 : W3;
    ushort_t* T = (w == 0) ? T0 : (w == 1) ? T1 : (w == 2) ? T2 : T3;
    T[j] = f2bf(W[k * DIM + n]);
}

// ---------- CSR build via two-level bucket counting sort ----------
// Device-scope atomics execute at the coherence point on 8-XCD parts and cap
// at ~13 G ops/s; LDS histograms + ~0.2M global reservations avoid that tax.

__global__ __launch_bounds__(256) void k_bhist(const int* __restrict__ dst, int E, int NB,
                                               int* __restrict__ bucketCount) {
    __shared__ int hist[512];
    int t = threadIdx.x;
    for (int b = t; b < NB; b += 256) hist[b] = 0;
    __syncthreads();
    int per = (E + gridDim.x - 1) / gridDim.x;
    int beg = blockIdx.x * per, end = min(beg + per, E);
    for (int i = beg + t; i < end; i += 256)
        atomicAdd(&hist[dst[i] >> BSHIFT], 1);
    __syncthreads();
    for (int b = t; b < NB; b += 256) {
        int v = hist[b];
        if (v) atomicAdd(&bucketCount[b], v);
    }
}

__global__ __launch_bounds__(512) void k_bscan(const int* __restrict__ bucketCount, int NB, int E,
                                               int* __restrict__ bucketBase,
                                               int* __restrict__ bucketCursor,
                                               int* __restrict__ row_ptr, int N) {
    __shared__ int lds[512];
    int t = threadIdx.x;
    int v = (t < NB) ? bucketCount[t] : 0;
    lds[t] = v;
    __syncthreads();
    for (int off = 1; off < 512; off <<= 1) {
        int u = (t >= off) ? lds[t - off] : 0;
        __syncthreads();
        lds[t] += u;
        __syncthreads();
    }
    if (t < NB) {
        int b = lds[t] - v;
        bucketBase[t] = b;
        bucketCursor[t] = b;
    }
    if (t == 0) row_ptr[N] = E;
}

__global__ __launch_bounds__(256) void k_bucketize(const int* __restrict__ src,
                                                   const int* __restrict__ dst, int E, int NB,
                                                   int* __restrict__ bucketCursor,
                                                   uint_t* __restrict__ bebuf) {
    __shared__ int hist[512];
    __shared__ int base[512];
    int t = threadIdx.x;
    for (int b = t; b < NB; b += 256) hist[b] = 0;
    __syncthreads();
    int per = (E + gridDim.x - 1) / gridDim.x;
    int beg = blockIdx.x * per, end = min(beg + per, E);
    for (int i = beg + t; i < end; i += 256)
        atomicAdd(&hist[dst[i] >> BSHIFT], 1);
    __syncthreads();
    for (int b = t; b < NB; b += 256) {
        int v = hist[b];
        base[b] = v ? atomicAdd(&bucketCursor[b], v) : 0;
        hist[b] = 0;
    }
    __syncthreads();
    for (int i = beg + t; i < end; i += 256) {
        int d = dst[i], s = src[i];
        int b = d >> BSHIFT;
        int off = atomicAdd(&hist[b], 1);
        bebuf[base[b] + off] = ((uint_t)(d & (BNODES - 1)) << 24) | (uint_t)s;
    }
}

__global__ __launch_bounds__(256) void k_bcsr(const uint_t* __restrict__ bebuf,
                                              const int* __restrict__ bucketBase,
                                              const int* __restrict__ bucketCount, int N,
                                              int* __restrict__ row_ptr, int* __restrict__ csr) {
    __shared__ int hist[BNODES];
    __shared__ int cur[BNODES];
    int t = threadIdx.x;
    int b = blockIdx.x;
    int ebase = bucketBase[b], cnt = bucketCount[b];
    int nodeBase = b << BSHIFT;
    hist[t] = 0;
    __syncthreads();
    for (int i = t; i < cnt; i += 256)
        atomicAdd(&hist[bebuf[ebase + i] >> 24], 1);
    __syncthreads();
    int v = hist[t];
    for (int off = 1; off < 256; off <<= 1) {
        int u = (t >= off) ? hist[t - off] : 0;
        __syncthreads();
        hist[t] += u;
        __syncthreads();
    }
    int excl = hist[t] - v;
    int node = nodeBase + t;
    if (node < N) row_ptr[node] = ebase + excl;
    cur[t] = excl;
    __syncthreads();
    for (int i = t; i < cnt; i += 256) {
        uint_t e = bebuf[ebase + i];
        int dl = (int)(e >> 24);
        int pos = atomicAdd(&cur[dl], 1);
        csr[ebase + pos] = (int)(e & 0xFFFFFFu);
    }
}

// ---------- mean aggregation: 16 lanes per node, x4 edge unroll ----------

__device__ __forceinline__ void acc8(float* a, uint4 p) {
    a[0] += bf2f((ushort_t)(p.x & 0xffffu));
    a[1] += bf2f((ushort_t)(p.x >> 16));
    a[2] += bf2f((ushort_t)(p.y & 0xffffu));
    a[3] += bf2f((ushort_t)(p.y >> 16));
    a[4] += bf2f((ushort_t)(p.z & 0xffffu));
    a[5] += bf2f((ushort_t)(p.z >> 16));
    a[6] += bf2f((ushort_t)(p.w & 0xffffu));
    a[7] += bf2f((ushort_t)(p.w >> 16));
}

__global__ __launch_bounds__(256) void k_agg(const ushort_t* __restrict__ X,
                                             const int* __restrict__ row_ptr,
                                             const int* __restrict__ csr,
                                             ushort_t* __restrict__ out, int n) {
    int node = (int)((blockIdx.x * (unsigned)blockDim.x + threadIdx.x) >> 4);
    if (node >= n) return;
    int sl = threadIdx.x & 15;               // sub-lane: 8 bf16 = 16 B of the row
    int beg = row_ptr[node], end = row_ptr[node + 1];
    float a[8] = {0.f, 0.f, 0.f, 0.f, 0.f, 0.f, 0.f, 0.f};

    int e = beg;
    for (; e + 4 <= end; e += 4) {
        int s0 = csr[e + 0], s1 = csr[e + 1], s2 = csr[e + 2], s3 = csr[e + 3];
        uint4 p0 = *(const uint4*)(X + (size_t)s0 * DIM + sl * 8);
        uint4 p1 = *(const uint4*)(X + (size_t)s1 * DIM + sl * 8);
        uint4 p2 = *(const uint4*)(X + (size_t)s2 * DIM + sl * 8);
        uint4 p3 = *(const uint4*)(X + (size_t)s3 * DIM + sl * 8);
        acc8(a, p0); acc8(a, p1); acc8(a, p2); acc8(a, p3);
    }
    for (; e < end; e++) {
        int s = csr[e];
        uint4 p = *(const uint4*)(X + (size_t)s * DIM + sl * 8);
        acc8(a, p);
    }

    int cnt = end - beg;
    float sc = (cnt > 0) ? 1.f / (float)cnt : 0.f;
    uint4 o;
    o.x = (uint_t)f2bf(a[0] * sc) | ((uint_t)f2bf(a[1] * sc) << 16);
    o.y = (uint_t)f2bf(a[2] * sc) | ((uint_t)f2bf(a[3] * sc) << 16);
    o.z = (uint_t)f2bf(a[4] * sc) | ((uint_t)f2bf(a[5] * sc) << 16);
    o.w = (uint_t)f2bf(a[6] * sc) | ((uint_t)f2bf(a[7] * sc) << 16);
    *(uint4*)(out + (size_t)node * DIM + sl * 8) = o;
}

// ---------- fused GEMM with LDS-staged weights ----------
// out = A1*W_l + A2*W_r + b; 32 rows/wave, 128 rows/block (4 waves).
// Both WT tables (64 KB) staged once per block, XOR-swizzled at 16 B-chunk
// granularity: chunk c of row n stored at c ^ (n&15) so ds_read_b128
// fragment reads are <=2-way bank-aliased (free, m136).
// MFMA 16x16x32 bf16 layouts (m89-verified):
//   A frag: lane holds A[m=lane&15][k=quad*8+j]
//   B frag: lane holds B[k=quad*8+j][n=lane&15] = WT[n=lane&15][k=quad*8+j]
//   C/D   : col=lane&15, row=quad*4+reg

template <bool RELU, bool OUT_BF16>
__global__ __launch_bounds__(256) void k_gemm(const ushort_t* __restrict__ A1,
                                              const ushort_t* __restrict__ A2,
                                              const ushort_t* __restrict__ WTl,
                                              const ushort_t* __restrict__ WTr,
                                              const float* __restrict__ bias,
                                              void* __restrict__ Out, int n_waves, int M) {
    __shared__ ushort_t sW[2 * 128 * 128];   // 64 KB
    int t = threadIdx.x;
    int wave = (int)((blockIdx.x * 256u + t) >> 6);
    int lane = t & 63;
    int col = lane & 15;
    int quad = lane >> 4;
    bool active = (wave < n_waves);

    // A-fragment loads issued first: their latency overlaps staging + barrier.
    bf16x8 a[2][8];
    if (active) {
#pragma unroll
        for (int tt = 0; tt < 2; tt++) {
            int arow = wave * 32 + tt * 16 + col;
            const ushort_t* a1p = A1 + (size_t)arow * DIM + quad * 8;
            const ushort_t* a2p = A2 + (size_t)arow * DIM + quad * 8;
#pragma unroll
            for (int ks = 0; ks < 4; ks++) a[tt][ks] = *(const bf16x8*)(a1p + ks * 32);
#pragma unroll
            for (int ks = 0; ks < 4; ks++) a[tt][4 + ks] = *(const bf16x8*)(a2p + ks * 32);
        }
    }

    // stage weights: thread t copies one row (t>>7 selects table, t&127 the row)
    {
        int tab = t >> 7, row = t & 127;
        const ushort_t* g = (tab ? WTr : WTl) + (size_t)row * 128;
        ushort_t* d = sW + (size_t)t * 128;
        int sw = row & 15;
#pragma unroll
        for (int c = 0; c < 16; c++) {
            uint4 v = *(const uint4*)(g + c * 8);
            *(uint4*)(d + ((c ^ sw) * 8)) = v;
        }
    }
    __syncthreads();
    if (!active) return;

    f32x4 acc[2][8];
#pragma unroll
    for (int tt = 0; tt < 2; tt++)
#pragma unroll
        for (int nt = 0; nt < 8; nt++) acc[tt][nt] = (f32x4){0.f, 0.f, 0.f, 0.f};

    const ushort_t* sWl = sW;
    const ushort_t* sWr = sW + 128 * 128;
#pragma unroll
    for (int nt = 0; nt < 8; nt++) {
        int row = nt * 16 + col;
        const ushort_t* bl = sWl + (size_t)row * 128;
        const ushort_t* br = sWr + (size_t)row * 128;
#pragma unroll
        for (int ks = 0; ks < 4; ks++) {
            bf16x8 b = *(const bf16x8*)(bl + (((ks * 4 + quad) ^ col) * 8));
            acc[0][nt] = __builtin_amdgcn_mfma_f32_16x16x32_bf16(a[0][ks], b, acc[0][nt], 0, 0, 0);
            acc[1][nt] = __builtin_amdgcn_mfma_f32_16x16x32_bf16(a[1][ks], b, acc[1][nt], 0, 0, 0);
        }
#pragma unroll
        for (int ks = 0; ks < 4; ks++) {
            bf16x8 b = *(const bf16x8*)(br + (((ks * 4 + quad) ^ col) * 8));
            acc[0][nt] = __builtin_amdgcn_mfma_f32_16x16x32_bf16(a[0][4 + ks], b, acc[0][nt], 0, 0, 0);
            acc[1][nt] = __builtin_amdgcn_mfma_f32_16x16x32_bf16(a[1][4 + ks], b, acc[1][nt], 0, 0, 0);
        }
    }

#pragma unroll
    for (int tt = 0; tt < 2; tt++)
#pragma unroll
        for (int nt = 0; nt < 8; nt++) {
            int c = nt * 16 + col;
            float bv = bias[c];
#pragma unroll
            for (int r = 0; r < 4; r++) {
                int m = wave * 32 + tt * 16 + quad * 4 + r;
                if (m < M) {
                    float v = acc[tt][nt][r] + bv;
                    if (RELU) v = v > 0.f ? v : 0.f;
                    if (OUT_BF16)
                        ((ushort_t*)Out)[(size_t)m * DIM + c] = f2bf(v);
                    else
                        ((float*)Out)[(size_t)m * DIM + c] = v;
                }
            }
        }
}

// ---------- host ----------

extern "C" void kernel_launch(void* const* d_in, const int* in_sizes, int n_in,
                              void* d_out, int out_size, void* d_ws, size_t ws_size,
                              hipStream_t stream) {
    const int N = in_sizes[0] / DIM;   // 100000
    const int E = in_sizes[1] / 2;     // 1600000
    const int NB = (N + BNODES - 1) >> BSHIFT;   // 391 buckets

    const float* x   = (const float*)d_in[0];
    const int*   ei  = (const int*)d_in[1];
    const int*   src = ei;
    const int*   dst = ei + E;
    const float* W1l = (const float*)d_in[2];
    const float* b1  = (const float*)d_in[3];
    const float* W1r = (const float*)d_in[4];
    const float* W2l = (const float*)d_in[5];
    const float* b2  = (const float*)d_in[6];
    const float* W2r = (const float*)d_in[7];
    float* out = (float*)d_out;

    char* ws = (char*)d_ws;
    size_t off = 0;
    auto alloc = [&](size_t bytes) -> char* {
        char* p = ws + off;
        off = (off + bytes + 255) & ~(size_t)255;
        return p;
    };

    int*      bucketCount  = (int*)alloc((size_t)NB * 4);
    int*      bucketBase   = (int*)alloc((size_t)NB * 4);
    int*      bucketCursor = (int*)alloc((size_t)NB * 4);
    int*      row_ptr      = (int*)alloc((size_t)(N + 1) * 4);
    int*      csr          = (int*)alloc((size_t)E * 4);
    uint_t*   bebuf        = (uint_t*)alloc((size_t)E * 4);
    size_t    fpad         = (size_t)32 * DIM * 2;   // tile-padding for MFMA A loads
    ushort_t* xb           = (ushort_t*)alloc((size_t)N * DIM * 2 + fpad);
    ushort_t* hb           = (ushort_t*)alloc((size_t)N * DIM * 2 + fpad);
    ushort_t* aggb         = (ushort_t*)alloc((size_t)N * DIM * 2 + fpad);
    ushort_t* wt1l         = (ushort_t*)alloc((size_t)DIM * DIM * 2);
    ushort_t* wt1r         = (ushort_t*)alloc((size_t)DIM * DIM * 2);
    ushort_t* wt2l         = (ushort_t*)alloc((size_t)DIM * DIM * 2);
    ushort_t* wt2r         = (ushort_t*)alloc((size_t)DIM * DIM * 2);

    // zero bucket histogram (ws is poisoned each call)
    hipMemsetAsync(bucketCount, 0, (size_t)NB * 4, stream);

    // x -> bf16
    {
        int n4 = N * DIM / 4;
        k_cvt_f32_bf16<<<dim3((n4 + 255) / 256), dim3(256), 0, stream>>>(x, xb, n4);
    }
    // weights -> transposed bf16 (single launch)
    k_wt4<<<dim3(4 * DIM * DIM / 256), dim3(256), 0, stream>>>(W1l, W1r, W2l, W2r,
                                                               wt1l, wt1r, wt2l, wt2r);
    // CSR build: bucket counting sort
    k_bhist<<<dim3(256), dim3(256), 0, stream>>>(dst, E, NB, bucketCount);
    k_bscan<<<dim3(1), dim3(512), 0, stream>>>(bucketCount, NB, E, bucketBase, bucketCursor, row_ptr, N);
    k_bucketize<<<dim3(256), dim3(256), 0, stream>>>(src, dst, E, NB, bucketCursor, bebuf);
    k_bcsr<<<dim3(NB), dim3(256), 0, stream>>>(bebuf, bucketBase, bucketCount, N, row_ptr, csr);

    const int n_waves = (N + 31) / 32;                          // 3125 (32 rows/wave)
    dim3 gemm_grid((n_waves + 3) / 4), gemm_blk(256);
    dim3 agg_grid((N + 15) / 16), agg_blk(256);                 // 16 nodes/block (16 lanes/node)

    // layer 1
    k_agg<<<agg_grid, agg_blk, 0, stream>>>(xb, row_ptr, csr, aggb, N);
    k_gemm<true, true><<<gemm_grid, gemm_blk, 0, stream>>>(aggb, xb, wt1l, wt1r, b1, hb, n_waves, N);
    // layer 2
    k_agg<<<agg_grid, agg_blk, 0, stream>>>(hb, row_ptr, csr, aggb, N);
    k_gemm<false, false><<<gemm_grid, gemm_blk, 0, stream>>>(aggb, hb, wt2l, wt2r, b2, out, n_waves, N);

    (void)n_in; (void)out_size; (void)ws_size;
}